// Round 5
// baseline (3747.766 us; speedup 1.0000x reference)
//
#include <hip/hip_runtime.h>
#include <hip/hip_bf16.h>

// out[b,n,f] = sum_{l,m} cg[l,m,n] * x1[b,l,f] * x2[b,m,f]
// B=20000, L=16, LOUT=49 (padded 64), F=512.
// Block = (b, f-half): GEMM OUT[64,256] = CG^T[64,256](bf16) * O[256,256],
// O[l*16+m, f] = bf16(x1[l,f]*x2[m,f]) built in registers from f32 LDS.
// 32 KB LDS/block -> 3 blocks/CU (reg-capped), reused for coalesced epilogue.

#define TP_L    16
#define TP_NOUT 49
#define TP_F    512
#define HF      256

typedef short short8 __attribute__((ext_vector_type(8)));
typedef float f32x4  __attribute__((ext_vector_type(4)));

static __device__ __forceinline__ short f2bf(float f) {
    unsigned u = __float_as_uint(f);
    u += 0x7fffu + ((u >> 16) & 1u);
    return (short)(u >> 16);
}

// cgT[n][k] = bf16(cg[l][m][n]), k = l*16+m, n padded to 64. cg flat: k*49+n.
__global__ void prep_cg_kernel(const float* __restrict__ cg, short* __restrict__ cgT) {
    int idx = blockIdx.x * 256 + threadIdx.x;   // 64*256
    int n = idx >> 8;
    int k = idx & 255;
    float v = (n < TP_NOUT) ? cg[k * TP_NOUT + n] : 0.0f;
    cgT[idx] = f2bf(v);
}

__global__ void __launch_bounds__(512, 6) tp_kernel(
    const float* __restrict__ x1, const float* __restrict__ x2,
    const short* __restrict__ cgT, float* __restrict__ out)
{
    __shared__ float smem[8192];     // 32 KB: sx1 [16][256] | sx2 [16][256]; reused by epilogue

    const int bid  = blockIdx.x;
    const int b    = bid >> 1;
    const int half = bid & 1;
    const int tid  = threadIdx.x;

    const float* x1b = x1 + (size_t)b * (TP_L * TP_F) + half * HF;
    const float* x2b = x2 + (size_t)b * (TP_L * TP_F) + half * HF;

    // ---- stage x1,x2 halves into LDS as f32 [16][256], f32x4-coalesced ----
#pragma unroll
    for (int i = 0; i < 2; ++i) {
        const int idx = tid + i * 512;          // [0,1024) f32x4 per matrix
        const int row = idx >> 6, c4 = idx & 63;
        ((f32x4*)smem)[idx]        = *(const f32x4*)(x1b + row * TP_F + c4 * 4);
        ((f32x4*)smem)[1024 + idx] = *(const f32x4*)(x2b + row * TP_F + c4 * 4);
    }
    __syncthreads();

    const float* sx1 = smem;
    const float* sx2 = smem + 4096;

    const int lane = tid & 63;
    const int w    = tid >> 6;       // wave 0..7 -> f range [w*32, w*32+32) within half
    const int fl   = lane & 15;
    const int g    = lane >> 4;      // 0..3
    const int hg   = g >> 1;         // l parity within K=32 step
    const int qg   = g & 1;          // m octet
    const int wf   = w * 32;

    f32x4 acc[4][2];                 // [n-tile][f-tile]
#pragma unroll
    for (int nt = 0; nt < 4; ++nt)
#pragma unroll
        for (int ft = 0; ft < 2; ++ft)
            acc[nt][ft] = (f32x4){0.f, 0.f, 0.f, 0.f};

    // ---- K loop: k = 32s + 8g + i ; l = 2s+hg, m = 8qg+i ----
#pragma unroll
    for (int s = 0; s < 8; ++s) {
        short8 a[4];
#pragma unroll
        for (int nt = 0; nt < 4; ++nt)
            a[nt] = *(const short8*)(cgT + (nt * 16 + fl) * 256 + s * 32 + g * 8);
#pragma unroll
        for (int ft = 0; ft < 2; ++ft) {
            const int f = wf + ft * 16 + fl;
            const float x1v = sx1[(2 * s + hg) * HF + f];
            const float* x2c = &sx2[(qg * 8) * HF + f];
            short8 bfr;
#pragma unroll
            for (int i = 0; i < 8; ++i)
                bfr[i] = f2bf(x1v * x2c[i * HF]);
#pragma unroll
            for (int nt = 0; nt < 4; ++nt)
                acc[nt][ft] = __builtin_amdgcn_mfma_f32_16x16x32_bf16(
                    a[nt], bfr, acc[nt][ft], 0, 0, 0);
        }
    }

    // ---- epilogue via LDS reuse: plain coalesced f32x4 stores ----
    // acc[nt][ft][j] = OUT[n = nt*16 + g*4 + j][fc = wf + ft*16 + fl]
    float* outb = out + (size_t)b * (TP_NOUT * TP_F) + half * HF;

    __syncthreads();                 // done reading sx1/sx2

    // chunk 0: n in [0,32) -> 32*256 floats = 32 KB (exact LDS reuse)
#pragma unroll
    for (int nt = 0; nt < 2; ++nt)
#pragma unroll
        for (int j = 0; j < 4; ++j)
#pragma unroll
            for (int ft = 0; ft < 2; ++ft)
                smem[(nt * 16 + g * 4 + j) * HF + wf + ft * 16 + fl] = acc[nt][ft][j];
    __syncthreads();
#pragma unroll
    for (int it = 0; it < 4; ++it) {
        const int idx = it * 512 + tid;          // [0,2048) f32x4
        const int row = idx >> 6, c4 = idx & 63;
        *(f32x4*)(outb + (size_t)row * TP_F + c4 * 4) = ((const f32x4*)smem)[idx];
    }
    __syncthreads();                 // done reading chunk-0 staging

    // chunk 1: n in [32,49) -> 17 rows
#pragma unroll
    for (int j = 0; j < 4; ++j)
#pragma unroll
        for (int ft = 0; ft < 2; ++ft)
            smem[(g * 4 + j) * HF + wf + ft * 16 + fl] = acc[2][ft][j];
    if (g == 0) {
#pragma unroll
        for (int ft = 0; ft < 2; ++ft)
            smem[16 * HF + wf + ft * 16 + fl] = acc[3][ft][0];
    }
    __syncthreads();
#pragma unroll
    for (int it = 0; it < 3; ++it) {
        const int idx = it * 512 + tid;
        if (idx < 17 * 64) {
            const int row = idx >> 6, c4 = idx & 63;
            *(f32x4*)(outb + (size_t)(32 + row) * TP_F + c4 * 4) = ((const f32x4*)smem)[idx];
        }
    }
}

extern "C" void kernel_launch(void* const* d_in, const int* in_sizes, int n_in,
                              void* d_out, int out_size, void* d_ws, size_t ws_size,
                              hipStream_t stream) {
    const float* x1 = (const float*)d_in[0];
    const float* x2 = (const float*)d_in[1];
    const float* cg = (const float*)d_in[2];
    float* out = (float*)d_out;
    short* cgT = (short*)d_ws;       // 64*256*2 = 32 KB scratch

    const int B = in_sizes[0] / (TP_L * TP_F);

    prep_cg_kernel<<<64, 256, 0, stream>>>(cg, cgT);
    tp_kernel<<<2 * B, 512, 0, stream>>>(x1, x2, cgT, out);
}